// Round 19
// baseline (182.707 us; speedup 1.0000x reference)
//
#include <hip/hip_runtime.h>
#include <hip/hip_bf16.h>
#include <math.h>
#include <stdint.h>

#define B 8
#define S 4096
#define D 256
#define H 256
#define FEAT 1794
#define R (B*S)
#define DH (D*H)
#define NCH 64   // s-chunks; chunk = 64

typedef __bf16 bf16_t;
typedef __bf16 bf16x8 __attribute__((ext_vector_type(8)));
typedef float f32x4 __attribute__((ext_vector_type(4)));

__device__ __forceinline__ float waveReduceSum(float v) {
  #pragma unroll
  for (int off = 32; off; off >>= 1) v += __shfl_xor(v, off, 64);
  return v;
}

// ---------- once-per-launch: CBF, 7 weight panels, WDQ/WDM, vq, hb0, m0, zeros ----
__global__ void k_init(const float* __restrict__ c, const float* __restrict__ q,
                       const float* __restrict__ w1, const float* __restrict__ A,
                       const float* __restrict__ b1, const int* __restrict__ len_c,
                       bf16_t* __restrict__ CBF,
                       bf16_t* __restrict__ WC,  bf16_t* __restrict__ WCQ,
                       bf16_t* __restrict__ WCM, bf16_t* __restrict__ WCQM,
                       bf16_t* __restrict__ WAQ, bf16_t* __restrict__ WAM,
                       bf16_t* __restrict__ WAQM,
                       float* __restrict__ WDQ, float* __restrict__ WDM,
                       float* __restrict__ vq, float* __restrict__ hb,
                       float* __restrict__ m0, float* __restrict__ epart,
                       float* __restrict__ ssum) {
  const int PREC_BLKS = R*D/2048;         // 4096 (8 rows per block)
  const int W_BLKS = DH/256;              // 256
  const int V_BLKS = B*64;
  const int blk = blockIdx.x;
  if (blk < PREC_BLKS) {
    const int row0 = blk * 8;
    const int b = row0 >> 12;
    if ((row0 & 4095) >= len_c[b]) return;   // rows beyond len: CBF unused
    int gid = blk * 256 + threadIdx.x;    // R*D/8
    const float* cp = c + (size_t)gid*8;
    float cv[8];
    *(float4*)(cv)   = *(const float4*)(cp);
    *(float4*)(cv+4) = *(const float4*)(cp + 4);
    bf16x8 cb;
    #pragma unroll
    for (int i = 0; i < 8; i++) cb[i] = (bf16_t)cv[i];
    *(bf16x8*)(CBF + (size_t)gid*8) = cb;
  } else if (blk < PREC_BLKS + W_BLKS) {
    int idx = (blk - PREC_BLKS) * 256 + threadIdx.x;   // DH
    int h = idx >> 8, k = idx & 255;
    const float* w1h = w1 + (size_t)h * FEAT;
    float wc = w1h[k], wcq = w1h[3*D + k], wcm = w1h[4*D + k];
    float waq = w1h[5*D + k], wam = w1h[6*D + k];
    WC[idx]   = (bf16_t)wc;
    WCQ[idx]  = (bf16_t)wcq;
    WCM[idx]  = (bf16_t)wcm;
    WCQM[idx] = (bf16_t)(wcq + wcm);
    WAQ[idx]  = (bf16_t)waq;
    WAM[idx]  = (bf16_t)wam;
    WAQM[idx] = (bf16_t)(waq + wam);
    if (k == 0) { WDQ[h] = w1h[7*D]; WDM[h] = w1h[7*D + 1]; }
  } else if (blk < PREC_BLKS + W_BLKS + V_BLKS) {
    const int blk2 = blk - PREC_BLKS - W_BLKS;         // B*64
    const int b = blk2 >> 6;
    const int lane = threadIdx.x & 63, wave = threadIdx.x >> 6;
    const int t = (blk2 & 63)*4 + wave;
    const int l4 = lane * 4;
    float4 q4 = *(const float4*)(q + b*D + l4);
    float4 a4 = *(const float4*)(A + (size_t)t*D + l4);
    float s = a4.x*q4.x + a4.y*q4.y + a4.z*q4.z + a4.w*q4.w;
    s = waveReduceSum(s);
    if (lane == 0) vq[b*D + t] = s;
    // hop-0 hb: b1 + q·(W1m + W1q)  (m == q)
    const float* w1r = w1 + (size_t)t*FEAT;
    float2 wm0 = *(const float2*)(w1r + D + l4);
    float2 wm1 = *(const float2*)(w1r + D + l4 + 2);
    float2 wq0 = *(const float2*)(w1r + 2*D + l4);
    float2 wq1 = *(const float2*)(w1r + 2*D + l4 + 2);
    float sh = q4.x*(wm0.x + wq0.x) + q4.y*(wm0.y + wq0.y)
             + q4.z*(wm1.x + wq1.x) + q4.w*(wm1.y + wq1.y);
    sh = waveReduceSum(sh);
    if (lane == 0) hb[b*H + t] = b1[t] + sh;
    if (threadIdx.x < 4) {
      const int tt = (blk2 & 63)*4 + threadIdx.x;
      m0[b*D + tt] = q[b*D + tt];
    }
  } else {
    // zero epart/ssum for dead chunks (never written by compacted score grid)
    const int b = blk - PREC_BLKS - W_BLKS - V_BLKS;   // B blocks
    const int ch0 = (len_c[b] + 63) >> 6;
    for (int ch = ch0; ch < NCH; ch++) {
      epart[(ch*B + b)*D + threadIdx.x] = 0.f;
      if (threadIdx.x == 0) ssum[ch*B + b] = 0.f;
    }
  }
}

// ---------- per-hop (hops 1,2 only) ----------

// vm[b][t] = A[t,:].m ; hb[b][t] = b1[t] + q.w1[t][2D:3D] + m.w1[t][D:2D]
__global__ void k_pm2(const float* __restrict__ A, const float* __restrict__ w1,
                      const float* __restrict__ b1, const float* __restrict__ q,
                      const float* __restrict__ min_,
                      float* __restrict__ vm, float* __restrict__ hb) {
  const int blk = blockIdx.x;              // B*64
  const int b = blk >> 6;
  const int lane = threadIdx.x & 63, wave = threadIdx.x >> 6;
  const int t = (blk & 63)*4 + wave;
  const int l4 = lane * 4;
  float4 m4 = *(const float4*)(min_ + b*D + l4);
  float4 q4 = *(const float4*)(q + b*D + l4);
  float4 a4 = *(const float4*)(A + (size_t)t*D + l4);
  const float* w1r = w1 + (size_t)t*FEAT;
  float2 wm0 = *(const float2*)(w1r + D + l4);
  float2 wm1 = *(const float2*)(w1r + D + l4 + 2);
  float2 wq0 = *(const float2*)(w1r + 2*D + l4);
  float2 wq1 = *(const float2*)(w1r + 2*D + l4 + 2);
  float sv = a4.x*m4.x + a4.y*m4.y + a4.z*m4.z + a4.w*m4.w;
  float sh = m4.x*wm0.x + m4.y*wm0.y + m4.z*wm1.x + m4.w*wm1.y
           + q4.x*wq0.x + q4.y*wq0.y + q4.z*wq1.x + q4.w*wq1.y;
  sv = waveReduceSum(sv);
  sh = waveReduceSum(sh);
  if (lane == 0) { vm[b*D + t] = sv; hb[b*H + t] = b1[t] + sh; }
}

// MFMA score v12: on-the-fly combined B stream (no WCB/comb), rank-1 dot
// terms in f32 epilogue, compacted grid, exp epilogue + fused ssum/epart.
// NS==3: streams {c·(Wc+q⊙Wcq+m⊙Wcm), |c-q|·Waq, |c-m|·Wam} + dq·wdq + dm·wdm
// NS==2 (hop0, m==q): {c·(Wc+q⊙Wcqm), |c-q|·Waqm} + dq·(wdq+wdm)
template<int NS>
__global__ __launch_bounds__(512, 4) void k_score12(
    const bf16_t* __restrict__ CBF,
    const bf16_t* __restrict__ WCp, const bf16_t* __restrict__ WCQp,
    const bf16_t* __restrict__ WCMp,
    const bf16_t* __restrict__ WAQp, const bf16_t* __restrict__ WAMp,
    const float* __restrict__ WDQ, const float* __restrict__ WDM,
    const float* __restrict__ q, const float* __restrict__ min_,
    const float* __restrict__ vqp, const float* __restrict__ vmp,
    const int* __restrict__ len_c,
    const float* __restrict__ hb, const float* __restrict__ w2,
    const float* __restrict__ b2, float* __restrict__ esc,
    float* __restrict__ epart, float* __restrict__ ssum) {
  // ---- compaction: flat block -> (b, r0l) over surviving 64-row tiles ----
  int b = 0, r0l = -1, accb = 0;
  const int flat = blockIdx.x;
  #pragma unroll
  for (int bb = 0; bb < 8; bb++) {
    const int nb = (len_c[bb] + 63) >> 6;
    if (r0l < 0 && flat < accb + nb) { b = bb; r0l = (flat - accb) << 6; }
    accb += nb;
  }
  if (r0l < 0) return;
  const int len = len_c[b];
  const int rowg = b*S + r0l;

  __shared__ char smem[49152];             // 3 streams x 16 KB (2 sub-chunks x 8 KB)
  __shared__ float qshf[256], mshf[256], vqshf[256], vmshf[256];
  __shared__ float red[8][64];
  __shared__ float esh2[64];
  __shared__ float dqsh[64], dmsh[64];
  const int t = threadIdx.x;
  const int lane = t & 63, wave = t >> 6;
  const int lrow = lane & 15;
  const int lk = (lane >> 4) * 8;
  const int n0 = wave * 32;

  if (t < 256) {
    qshf[t] = q[b*D + t];
    mshf[t] = min_[b*D + t];
    vqshf[t] = vqp[b*D + t];
    if (NS == 3) vmshf[t] = vmp[b*D + t];
  }

  const int srow = t >> 3, sl = t & 7;
  const int sp = sl ^ (srow & 7);
  const int swbase = srow*128 + sp*16;
  const bf16_t* cgp = CBF + (size_t)(rowg + srow)*D + sl*8;

  f32x4 acc[4][2];
  #pragma unroll
  for (int mi = 0; mi < 4; mi++)
    #pragma unroll
    for (int ni = 0; ni < 2; ni++) acc[mi][ni] = (f32x4){0.f,0.f,0.f,0.f};

  float dqa = 0.f, dma = 0.f;

  bf16x8 breg[2][6];
  // LOADB: on-the-fly combined stream0 + static stream1(+2)
  #define LOADB(ks) { \
    const int kelem = (ks)*32 + lk; \
    float qv8[8], mv8[8]; \
    *(float4*)(qv8)   = *(const float4*)(qshf + kelem); \
    *(float4*)(qv8+4) = *(const float4*)(qshf + kelem + 4); \
    if (NS == 3) { \
      *(float4*)(mv8)   = *(const float4*)(mshf + kelem); \
      *(float4*)(mv8+4) = *(const float4*)(mshf + kelem + 4); \
    } \
    _Pragma("unroll") \
    for (int ni = 0; ni < 2; ni++) { \
      const size_t co = (size_t)(n0 + ni*16 + lrow) * D + kelem; \
      bf16x8 wcv  = *(const bf16x8*)(WCp + co); \
      bf16x8 wqv  = *(const bf16x8*)(WCQp + co); \
      bf16x8 wmv; \
      if (NS == 3) wmv = *(const bf16x8*)(WCMp + co); \
      bf16x8 combv; \
      _Pragma("unroll") \
      for (int i = 0; i < 8; i++) { \
        float v = (float)wcv[i] + qv8[i]*(float)wqv[i]; \
        if (NS == 3) v += mv8[i]*(float)wmv[i]; \
        combv[i] = (bf16_t)v; \
      } \
      breg[(ks)&1][ni*3+0] = combv; \
      breg[(ks)&1][ni*3+1] = *(const bf16x8*)(WAQp + co); \
      if (NS == 3) breg[(ks)&1][ni*3+2] = *(const bf16x8*)(WAMp + co); \
    } }

  #define STAGESC(mc, cc, cr) { \
    const int kof = (mc)*128 + (cc)*64 + sl*8; \
    float qv_[8], mv_[8]; \
    *(float4*)(qv_)   = *(const float4*)(qshf + kof); \
    *(float4*)(qv_+4) = *(const float4*)(qshf + kof + 4); \
    if (NS == 3) { \
      *(float4*)(mv_)   = *(const float4*)(mshf + kof); \
      *(float4*)(mv_+4) = *(const float4*)(mshf + kof + 4); \
    } \
    float vq_[8], vm_[8]; \
    *(float4*)(vq_)   = *(const float4*)(vqshf + kof); \
    *(float4*)(vq_+4) = *(const float4*)(vqshf + kof + 4); \
    if (NS == 3) { \
      *(float4*)(vm_)   = *(const float4*)(vmshf + kof); \
      *(float4*)(vm_+4) = *(const float4*)(vmshf + kof + 4); \
    } \
    bf16x8 aqv_, amv_; \
    _Pragma("unroll") \
    for (int i = 0; i < 8; i++) { \
      float cf_ = (float)(cr)[i]; \
      aqv_[i] = (bf16_t)fabsf(cf_ - qv_[i]); \
      if (NS == 3) amv_[i] = (bf16_t)fabsf(cf_ - mv_[i]); \
      dqa += cf_ * vq_[i]; \
      if (NS == 3) dma += cf_ * vm_[i]; \
    } \
    char* lb_ = smem + (cc)*8192 + swbase; \
    *(bf16x8*)(lb_)         = (cr); \
    *(bf16x8*)(lb_ + 16384) = aqv_; \
    if (NS == 3) *(bf16x8*)(lb_ + 32768) = amv_; \
  }

  bf16x8 cA = *(const bf16x8*)(cgp);        // mc0 cc0 (global only, pre-barrier)
  bf16x8 cB = *(const bf16x8*)(cgp + 64);   // mc0 cc1
  __syncthreads();                          // shared vectors visible
  LOADB(0);
  STAGESC(0, 0, cA);
  STAGESC(0, 1, cB);
  cA = *(const bf16x8*)(cgp + 128);         // mc1 prefetch
  cB = *(const bf16x8*)(cgp + 192);
  __syncthreads();                          // mc0 staged

  #pragma unroll
  for (int ks = 0; ks < 4; ks++) {
    LOADB(ks + 1);
    const int cc = ks >> 1, kk = ks & 1;
    const int p = ((kk << 2) + (lane >> 4)) ^ (lane & 7);
    const char* lb = smem + cc*8192;
    #pragma unroll
    for (int mi = 0; mi < 4; mi++) {
      const int ro = (mi*16 + lrow)*128 + p*16;
      bf16x8 ac = *(const bf16x8*)(lb + ro);
      bf16x8 aq = *(const bf16x8*)(lb + 16384 + ro);
      #pragma unroll
      for (int ni = 0; ni < 2; ni++) {
        acc[mi][ni] = __builtin_amdgcn_mfma_f32_16x16x32_bf16(ac, breg[ks&1][ni*3+0], acc[mi][ni], 0, 0, 0);
        acc[mi][ni] = __builtin_amdgcn_mfma_f32_16x16x32_bf16(aq, breg[ks&1][ni*3+1], acc[mi][ni], 0, 0, 0);
      }
      if (NS == 3) {
        bf16x8 am = *(const bf16x8*)(lb + 32768 + ro);
        #pragma unroll
        for (int ni = 0; ni < 2; ni++)
          acc[mi][ni] = __builtin_amdgcn_mfma_f32_16x16x32_bf16(am, breg[ks&1][ni*3+2], acc[mi][ni], 0, 0, 0);
      }
    }
  }
  __syncthreads();                          // mc0 reads done
  STAGESC(1, 0, cA);
  STAGESC(1, 1, cB);
  // rank-1 dot reduce over the 8 slot-lanes of each row
  {
    float dqv = dqa;
    dqv += __shfl_xor(dqv, 1, 64);
    dqv += __shfl_xor(dqv, 2, 64);
    dqv += __shfl_xor(dqv, 4, 64);
    if ((t & 7) == 0) dqsh[srow] = dqv;
    if (NS == 3) {
      float dmv = dma;
      dmv += __shfl_xor(dmv, 1, 64);
      dmv += __shfl_xor(dmv, 2, 64);
      dmv += __shfl_xor(dmv, 4, 64);
      if ((t & 7) == 0) dmsh[srow] = dmv;
    }
  }
  __syncthreads();                          // mc1 staged + dqsh visible

  #pragma unroll
  for (int ks = 4; ks < 8; ks++) {
    if (ks < 7) LOADB(ks + 1);
    const int cc = (ks >> 1) & 1, kk = ks & 1;
    const int p = ((kk << 2) + (lane >> 4)) ^ (lane & 7);
    const char* lb = smem + cc*8192;
    #pragma unroll
    for (int mi = 0; mi < 4; mi++) {
      const int ro = (mi*16 + lrow)*128 + p*16;
      bf16x8 ac = *(const bf16x8*)(lb + ro);
      bf16x8 aq = *(const bf16x8*)(lb + 16384 + ro);
      #pragma unroll
      for (int ni = 0; ni < 2; ni++) {
        acc[mi][ni] = __builtin_amdgcn_mfma_f32_16x16x32_bf16(ac, breg[ks&1][ni*3+0], acc[mi][ni], 0, 0, 0);
        acc[mi][ni] = __builtin_amdgcn_mfma_f32_16x16x32_bf16(aq, breg[ks&1][ni*3+1], acc[mi][ni], 0, 0, 0);
      }
      if (NS == 3) {
        bf16x8 am = *(const bf16x8*)(lb + 32768 + ro);
        #pragma unroll
        for (int ni = 0; ni < 2; ni++)
          acc[mi][ni] = __builtin_amdgcn_mfma_f32_16x16x32_bf16(am, breg[ks&1][ni*3+2], acc[mi][ni], 0, 0, 0);
      }
    }
  }

  // epilogue: + hb + dq*wdq + dm*wdm, tanh, w2-dot; esc = exp(score)
  float hbv[2], w2v[2], wdqv[2], wdmv[2];
  #pragma unroll
  for (int ni = 0; ni < 2; ni++) {
    const int col = n0 + ni*16 + lrow;
    hbv[ni] = hb[b*H + col];
    w2v[ni] = w2[col];
    wdqv[ni] = WDQ[col];
    wdmv[ni] = WDM[col];
  }
  #pragma unroll
  for (int mi = 0; mi < 4; mi++) {
    #pragma unroll
    for (int j = 0; j < 4; j++) {
      const int row = mi*16 + (lane >> 4)*4 + j;
      const float dqr = dqsh[row];
      const float dmr = (NS == 3) ? dmsh[row] : dqr;
      float ps = 0.f;
      #pragma unroll
      for (int ni = 0; ni < 2; ni++) {
        float x = acc[mi][ni][j] + hbv[ni] + dqr*wdqv[ni] + dmr*wdmv[ni];
        float ex = __expf(2.f * x);
        float th = 1.f - 2.f * __builtin_amdgcn_rcpf(ex + 1.f);
        ps += th * w2v[ni];
      }
      ps += __shfl_xor(ps, 1, 64);
      ps += __shfl_xor(ps, 2, 64);
      ps += __shfl_xor(ps, 4, 64);
      ps += __shfl_xor(ps, 8, 64);
      if (lrow == 0) red[wave][row] = ps;
    }
  }
  __syncthreads();
  const int ch = r0l >> 6;
  if (t < 64) {
    float s = red[0][t] + red[1][t] + red[2][t] + red[3][t]
            + red[4][t] + red[5][t] + red[6][t] + red[7][t] + b2[0];
    float ev = (r0l + t < len) ? __expf(s) : 0.f;
    esc[b*S + r0l + t] = ev;
    esh2[t] = ev;
    float v = waveReduceSum(ev);
    if (t == 0) ssum[ch*B + b] = v;
  }
  __syncthreads();

  // fused epart: 64x256 weighted sum of CBF rows (L2-hot) with esh2 weights.
  float* racc = (float*)smem;               // 16 x 256 floats (stage LDS dead)
  const int cg = t & 31, rg = t >> 5;       // 32 col-groups x 16 row-groups
  float a8[8];
  #pragma unroll
  for (int i = 0; i < 8; i++) a8[i] = 0.f;
  #pragma unroll
  for (int j = 0; j < 4; j++) {
    const int sr = rg + j*16;
    const bf16x8 cv = *(const bf16x8*)(CBF + (size_t)(rowg + sr)*D + cg*8);
    const float a = esh2[sr];
    #pragma unroll
    for (int i = 0; i < 8; i++) a8[i] += a * (float)cv[i];
  }
  *(float4*)(&racc[rg*256 + cg*8])     = *(float4*)(a8);
  *(float4*)(&racc[rg*256 + cg*8 + 4]) = *(float4*)(a8 + 4);
  __syncthreads();
  if (t < 256) {
    float s2 = 0.f;
    #pragma unroll
    for (int g = 0; g < 16; g++) s2 += racc[g*256 + t];
    epart[(ch*B + b)*D + t] = s2;
  }
}

// gru v3: T_b reduce + att write + normalized e + GRU gates. (NCH=64)
__global__ __launch_bounds__(256) void k_gru3(
    const float* __restrict__ wih, const float* __restrict__ whh,
    const float* __restrict__ bih, const float* __restrict__ bhh,
    const float* __restrict__ epart, const float* __restrict__ ssum,
    const float* __restrict__ esc, const int* __restrict__ len_c,
    const float* __restrict__ min_,
    float* __restrict__ att, float* __restrict__ mout,
    float* __restrict__ out, const int write_out) {
  const int blk = blockIdx.x;         // B*16
  const int b = blk >> 4;
  const int p = blk & 15;
  const int t = threadIdx.x;
  const int lane = t & 63, wave = t >> 6;
  const int len = len_c[b];
  __shared__ float es[D], ms[D];
  __shared__ float Tsh;
  if (t < 64) {
    float v = waveReduceSum(ssum[t*B + b]);
    if (t == 0) Tsh = v;
  }
  float e = 0.f;
  #pragma unroll
  for (int ch = 0; ch < NCH; ch++) e += epart[(ch*B + b)*D + t];
  ms[t] = min_[b*D + t];
  __syncthreads();
  const float Tinv = 1.f / Tsh;
  es[t] = e * Tinv;
  const int sI = p*256 + t;
  att[b*S + sI] = (sI < len) ? esc[b*S + sI] * Tinv : 0.f;
  __syncthreads();
  const int t0 = p << 4;
  const int l4 = lane * 4;
  float4 e4 = *(const float4*)(es + l4);
  float4 m4 = *(const float4*)(ms + l4);
  #pragma unroll
  for (int tl = 0; tl < 4; tl++) {
    const int tt = t0 + wave*4 + tl;
    float g[6];
    #pragma unroll
    for (int gg = 0; gg < 3; gg++) {
      const int j = gg*D + tt;
      const float4 wi4 = *(const float4*)(wih + (size_t)j*D + l4);
      const float4 wh4 = *(const float4*)(whh + (size_t)j*D + l4);
      float gi = e4.x*wi4.x + e4.y*wi4.y + e4.z*wi4.z + e4.w*wi4.w;
      float gh = m4.x*wh4.x + m4.y*wh4.y + m4.z*wh4.z + m4.w*wh4.w;
      g[gg]   = waveReduceSum(gi);
      g[3+gg] = waveReduceSum(gh);
    }
    if (lane == 0) {
      const int j0 = tt, j1 = D + tt, j2 = 2*D + tt;
      float gir = g[0] + bih[j0], giz = g[1] + bih[j1], gin = g[2] + bih[j2];
      float ghr = g[3] + bhh[j0], ghz = g[4] + bhh[j1], ghn = g[5] + bhh[j2];
      float rr = 1.f / (1.f + __expf(-(gir + ghr)));
      float zz = 1.f / (1.f + __expf(-(giz + ghz)));
      float nn = tanhf(gin + rr * ghn);
      float mn = (1.f - zz)*nn + zz*ms[tt];
      mout[b*D + tt] = mn;
      if (write_out) out[b*D + tt] = mn;
    }
  }
}

extern "C" void kernel_launch(void* const* d_in, const int* in_sizes, int n_in,
                              void* d_out, int out_size, void* d_ws, size_t ws_size,
                              hipStream_t stream) {
  const float* c   = (const float*)d_in[0];
  const float* q   = (const float*)d_in[1];
  const int*   len = (const int*)d_in[2];
  const float* A   = (const float*)d_in[3];
  const float* w1  = (const float*)d_in[4];
  const float* b1  = (const float*)d_in[5];
  const float* w2  = (const float*)d_in[6];
  const float* b2  = (const float*)d_in[7];
  const float* wih = (const float*)d_in[8];
  const float* whh = (const float*)d_in[9];
  const float* bih = (const float*)d_in[10];
  const float* bhh = (const float*)d_in[11];
  float* out = (float*)d_out;

  bf16_t* WC   = (bf16_t*)d_ws;
  bf16_t* WCQ  = WC + DH;
  bf16_t* WCM  = WCQ + DH;
  bf16_t* WCQM = WCM + DH;
  bf16_t* WAQ  = WCQM + DH;
  bf16_t* WAM  = WAQ + DH;
  bf16_t* WAQM = WAM + DH;
  bf16_t* CBF  = WAQM + DH;
  float* fb = (float*)(CBF + (size_t)R*D);
  float* WDQ   = fb;
  float* WDM   = WDQ + 256;
  float* vq    = WDM + 256;
  float* vm    = vq + B*D;
  float* hb    = vm + B*D;
  float* m0    = hb + B*H;
  float* m1    = m0 + B*D;
  float* epart = m1 + B*D;
  float* esc   = epart + (size_t)NCH*B*D;
  float* ssum  = esc + R;

  k_init<<<R*D/2048 + DH/256 + B*64 + B, 256, 0, stream>>>(
      c, q, w1, A, b1, len, CBF, WC, WCQ, WCM, WCQM, WAQ, WAM, WAQM,
      WDQ, WDM, vq, hb, m0, epart, ssum);

  for (int it = 0; it < 3; ++it) {
    float* min_ = (it & 1) ? m1 : m0;
    float* mout = (it & 1) ? m0 : m1;
    if (it == 0) {
      // hop 0: m == q -> vm = vq, hb from k_init, collapsed streams
      k_score12<2><<<R/64, 512, 0, stream>>>(
          CBF, WC, WCQM, WCM, WAQM, WAM, WDQ, WDM,
          q, min_, vq, vq, len, hb, w2, b2, esc, epart, ssum);
    } else {
      k_pm2<<<B*64, 256, 0, stream>>>(A, w1, b1, q, min_, vm, hb);
      k_score12<3><<<R/64, 512, 0, stream>>>(
          CBF, WC, WCQ, WCM, WAQ, WAM, WDQ, WDM,
          q, min_, vq, vm, len, hb, w2, b2, esc, epart, ssum);
    }
    float* att = out + B*D + (size_t)it*R;
    k_gru3<<<B*16, 256, 0, stream>>>(wih, whh, bih, bhh, epart, ssum, esc, len, min_, att, mout, out, it == 2 ? 1 : 0);
  }
}

// Round 20
// 129.483 us; speedup vs baseline: 1.4110x; 1.4110x over previous
//
#include <hip/hip_runtime.h>
#include <hip/hip_bf16.h>
#include <math.h>
#include <stdint.h>

#define B 8
#define S 4096
#define D 256
#define H 256
#define FEAT 1794
#define R (B*S)
#define DH (D*H)
#define NCH 64   // s-chunks; chunk = 64

typedef __bf16 bf16_t;
typedef __bf16 bf16x8 __attribute__((ext_vector_type(8)));
typedef float f32x4 __attribute__((ext_vector_type(4)));

__device__ __forceinline__ float waveReduceSum(float v) {
  #pragma unroll
  for (int off = 32; off; off >>= 1) v += __shfl_xor(v, off, 64);
  return v;
}

// ---------- once-per-launch: CBF, WAQ/WAM/WAQM, vq, hb0, m0, dead-chunk zeros ----
__global__ void k_init(const float* __restrict__ c, const float* __restrict__ q,
                       const float* __restrict__ w1, const float* __restrict__ A,
                       const float* __restrict__ b1, const int* __restrict__ len_c,
                       bf16_t* __restrict__ CBF, bf16_t* __restrict__ WAQ,
                       bf16_t* __restrict__ WAM, bf16_t* __restrict__ WAQM,
                       float* __restrict__ vq, float* __restrict__ hb,
                       float* __restrict__ m0, float* __restrict__ epart,
                       float* __restrict__ ssum) {
  const int PREC_BLKS = R*D/2048;         // 4096 (8 rows per block)
  const int W_BLKS = DH/256;              // 256
  const int V_BLKS = B*64;
  const int blk = blockIdx.x;
  if (blk < PREC_BLKS) {
    const int row0 = blk * 8;
    const int b = row0 >> 12;
    if ((row0 & 4095) >= len_c[b]) return;   // rows beyond len: CBF unused
    int gid = blk * 256 + threadIdx.x;    // R*D/8
    const float* cp = c + (size_t)gid*8;
    float cv[8];
    *(float4*)(cv)   = *(const float4*)(cp);
    *(float4*)(cv+4) = *(const float4*)(cp + 4);
    bf16x8 cb;
    #pragma unroll
    for (int i = 0; i < 8; i++) cb[i] = (bf16_t)cv[i];
    *(bf16x8*)(CBF + (size_t)gid*8) = cb;
  } else if (blk < PREC_BLKS + W_BLKS) {
    int idx = (blk - PREC_BLKS) * 256 + threadIdx.x;   // DH
    int h = idx >> 8, k = idx & 255;
    const float* w1h = w1 + (size_t)h * FEAT;
    float wq = w1h[5*D + k], wm = w1h[6*D + k];
    WAQ[idx]  = (bf16_t)wq;
    WAM[idx]  = (bf16_t)wm;
    WAQM[idx] = (bf16_t)(wq + wm);           // hop-0 collapsed stream
  } else if (blk < PREC_BLKS + W_BLKS + V_BLKS) {
    const int blk2 = blk - PREC_BLKS - W_BLKS;         // B*64
    const int b = blk2 >> 6;
    const int lane = threadIdx.x & 63, wave = threadIdx.x >> 6;
    const int t = (blk2 & 63)*4 + wave;
    const int l4 = lane * 4;
    float4 q4 = *(const float4*)(q + b*D + l4);
    float4 a4 = *(const float4*)(A + (size_t)t*D + l4);
    float s = a4.x*q4.x + a4.y*q4.y + a4.z*q4.z + a4.w*q4.w;
    s = waveReduceSum(s);
    if (lane == 0) vq[b*D + t] = s;
    // hop-0 hb: b1 + q·(W1m + W1q)  (m == q at hop 0)
    const float* w1r = w1 + (size_t)t*FEAT;
    float2 wm0 = *(const float2*)(w1r + D + l4);
    float2 wm1 = *(const float2*)(w1r + D + l4 + 2);
    float2 wq0 = *(const float2*)(w1r + 2*D + l4);
    float2 wq1 = *(const float2*)(w1r + 2*D + l4 + 2);
    float sh = q4.x*(wm0.x + wq0.x) + q4.y*(wm0.y + wq0.y)
             + q4.z*(wm1.x + wq1.x) + q4.w*(wm1.y + wq1.y);
    sh = waveReduceSum(sh);
    if (lane == 0) hb[b*H + t] = b1[t] + sh;
    if (threadIdx.x < 4) {
      const int tt = (blk2 & 63)*4 + threadIdx.x;
      m0[b*D + tt] = q[b*D + tt];
    }
  } else {
    // zero epart/ssum for dead chunks (never written by compacted score grid)
    const int b = blk - PREC_BLKS - W_BLKS - V_BLKS;   // B blocks
    const int ch0 = (len_c[b] + 63) >> 6;
    for (int ch = ch0; ch < NCH; ch++) {
      epart[(ch*B + b)*D + threadIdx.x] = 0.f;
      if (threadIdx.x == 0) ssum[ch*B + b] = 0.f;
    }
  }
}

// ---------- per-hop ----------

// vm[b][t] = A[t,:].m ; hb[b][t] = b1[t] + q.w1[t][2D:3D] + m.w1[t][D:2D]
// (hops 1,2 only)
__global__ void k_pm2(const float* __restrict__ A, const float* __restrict__ w1,
                      const float* __restrict__ b1, const float* __restrict__ q,
                      const float* __restrict__ min_,
                      float* __restrict__ vm, float* __restrict__ hb) {
  const int blk = blockIdx.x;              // B*64
  const int b = blk >> 6;
  const int lane = threadIdx.x & 63, wave = threadIdx.x >> 6;
  const int t = (blk & 63)*4 + wave;
  const int l4 = lane * 4;
  float4 m4 = *(const float4*)(min_ + b*D + l4);
  float4 q4 = *(const float4*)(q + b*D + l4);
  float4 a4 = *(const float4*)(A + (size_t)t*D + l4);
  const float* w1r = w1 + (size_t)t*FEAT;
  float2 wm0 = *(const float2*)(w1r + D + l4);
  float2 wm1 = *(const float2*)(w1r + D + l4 + 2);
  float2 wq0 = *(const float2*)(w1r + 2*D + l4);
  float2 wq1 = *(const float2*)(w1r + 2*D + l4 + 2);
  float sv = a4.x*m4.x + a4.y*m4.y + a4.z*m4.z + a4.w*m4.w;
  float sh = m4.x*wm0.x + m4.y*wm0.y + m4.z*wm1.x + m4.w*wm1.y
           + q4.x*wq0.x + q4.y*wq0.y + q4.z*wq1.x + q4.w*wq1.y;
  sv = waveReduceSum(sv);
  sh = waveReduceSum(sh);
  if (lane == 0) { vm[b*D + t] = sv; hb[b*H + t] = b1[t] + sh; }
}

// WCB[b][h][k] = Wc + q*Wcq + m*Wcm + vq[k]*wdq[h] + vm[k]*wdm[h]  (bf16)
__global__ void k_comb(const float* __restrict__ w1, const float* __restrict__ q,
                       const float* __restrict__ min_,
                       const float* __restrict__ vq, const float* __restrict__ vm,
                       bf16_t* __restrict__ WCB) {
  int idx = blockIdx.x * 256 + threadIdx.x;  // B*DH
  int b = idx >> 16;
  int h = (idx >> 8) & 255;
  int k = idx & 255;
  const float* w1h = w1 + (size_t)h * FEAT;
  float v = w1h[k] + q[b*D + k]*w1h[3*D + k] + min_[b*D + k]*w1h[4*D + k]
          + vq[b*D + k]*w1h[7*D] + vm[b*D + k]*w1h[7*D + 1];
  WCB[idx] = (bf16_t)v;
}

// MFMA score v8 (round-17 proven), templated on stream count.
// NS==3: streams {c, |c-q|·Waq, |c-m|·Wam}. NS==2: hop-0, {c, |c-q|·(Waq+Wam)}.
template<int NS>
__global__ __launch_bounds__(512, 4) void k_score8(
    const bf16_t* __restrict__ CBF,
    const bf16_t* __restrict__ WCB, const bf16_t* __restrict__ WAQ,
    const bf16_t* __restrict__ WAM,
    const float* __restrict__ q, const float* __restrict__ min_,
    const int* __restrict__ len_c,
    const float* __restrict__ hb, const float* __restrict__ w2,
    const float* __restrict__ b2, float* __restrict__ esc,
    float* __restrict__ epart, float* __restrict__ ssum) {
  // ---- compaction: flat block -> (b, r0l) over surviving 64-row tiles ----
  int b = 0, r0l = -1, accb = 0;
  const int flat = blockIdx.x;
  #pragma unroll
  for (int bb = 0; bb < 8; bb++) {
    const int nb = (len_c[bb] + 63) >> 6;
    if (r0l < 0 && flat < accb + nb) { b = bb; r0l = (flat - accb) << 6; }
    accb += nb;
  }
  if (r0l < 0) return;
  const int len = len_c[b];
  const int rowg = b*S + r0l;

  __shared__ char smem[49152];             // 3 streams x 16 KB (2 sub-chunks x 8 KB)
  __shared__ float qshf[256], mshf[256];
  __shared__ float red[8][64];
  __shared__ float esh2[64];
  const int t = threadIdx.x;
  const int lane = t & 63, wave = t >> 6;
  const int lrow = lane & 15;
  const int lk = (lane >> 4) * 8;
  const int n0 = wave * 32;

  if (t < 256) { qshf[t] = q[b*D + t]; mshf[t] = min_[b*D + t]; }

  const int srow = t >> 3, sl = t & 7;
  const int sp = sl ^ (srow & 7);
  const int swbase = srow*128 + sp*16;
  const bf16_t* cgp = CBF + (size_t)(rowg + srow)*D + sl*8;

  const bf16_t* bptrC = WCB + (size_t)b*DH;
  const bf16_t* bptrQ = WAQ;
  const bf16_t* bptrM = WAM;

  f32x4 acc[4][2];
  #pragma unroll
  for (int mi = 0; mi < 4; mi++)
    #pragma unroll
    for (int ni = 0; ni < 2; ni++) acc[mi][ni] = (f32x4){0.f,0.f,0.f,0.f};

  bf16x8 breg[2][6];
  #define LOADB(ks) { \
    const int kelem = (ks)*32 + lk; \
    _Pragma("unroll") \
    for (int ni = 0; ni < 2; ni++) { \
      const size_t co = (size_t)(n0 + ni*16 + lrow) * D + kelem; \
      breg[(ks)&1][ni*3+0] = *(const bf16x8*)(bptrC + co); \
      breg[(ks)&1][ni*3+1] = *(const bf16x8*)(bptrQ + co); \
      if (NS == 3) breg[(ks)&1][ni*3+2] = *(const bf16x8*)(bptrM + co); \
    } }

  #define STAGESC(mc, cc, cr) { \
    const int kof = (mc)*128 + (cc)*64 + sl*8; \
    float qv_[8], mv_[8]; \
    *(float4*)(qv_)   = *(const float4*)(qshf + kof); \
    *(float4*)(qv_+4) = *(const float4*)(qshf + kof + 4); \
    *(float4*)(mv_)   = *(const float4*)(mshf + kof); \
    *(float4*)(mv_+4) = *(const float4*)(mshf + kof + 4); \
    bf16x8 aqv_, amv_; \
    _Pragma("unroll") \
    for (int i = 0; i < 8; i++) { \
      float cf_ = (float)(cr)[i]; \
      aqv_[i] = (bf16_t)fabsf(cf_ - qv_[i]); \
      if (NS == 3) amv_[i] = (bf16_t)fabsf(cf_ - mv_[i]); \
    } \
    char* lb_ = smem + (cc)*8192 + swbase; \
    *(bf16x8*)(lb_)         = (cr); \
    *(bf16x8*)(lb_ + 16384) = aqv_; \
    if (NS == 3) *(bf16x8*)(lb_ + 32768) = amv_; \
  }

  bf16x8 cA = *(const bf16x8*)(cgp);        // mc0 cc0
  bf16x8 cB = *(const bf16x8*)(cgp + 64);   // mc0 cc1
  LOADB(0);
  __syncthreads();                          // qshf/mshf visible
  STAGESC(0, 0, cA);
  STAGESC(0, 1, cB);
  cA = *(const bf16x8*)(cgp + 128);         // mc1 prefetch
  cB = *(const bf16x8*)(cgp + 192);
  __syncthreads();                          // mc0 staged

  #pragma unroll
  for (int ks = 0; ks < 4; ks++) {
    LOADB(ks + 1);
    const int cc = ks >> 1, kk = ks & 1;
    const int p = ((kk << 2) + (lane >> 4)) ^ (lane & 7);
    const char* lb = smem + cc*8192;
    #pragma unroll
    for (int mi = 0; mi < 4; mi++) {
      const int ro = (mi*16 + lrow)*128 + p*16;
      bf16x8 ac = *(const bf16x8*)(lb + ro);
      bf16x8 aq = *(const bf16x8*)(lb + 16384 + ro);
      #pragma unroll
      for (int ni = 0; ni < 2; ni++) {
        acc[mi][ni] = __builtin_amdgcn_mfma_f32_16x16x32_bf16(ac, breg[ks&1][ni*3+0], acc[mi][ni], 0, 0, 0);
        acc[mi][ni] = __builtin_amdgcn_mfma_f32_16x16x32_bf16(aq, breg[ks&1][ni*3+1], acc[mi][ni], 0, 0, 0);
      }
      if (NS == 3) {
        bf16x8 am = *(const bf16x8*)(lb + 32768 + ro);
        #pragma unroll
        for (int ni = 0; ni < 2; ni++)
          acc[mi][ni] = __builtin_amdgcn_mfma_f32_16x16x32_bf16(am, breg[ks&1][ni*3+2], acc[mi][ni], 0, 0, 0);
      }
    }
  }
  __syncthreads();                          // mc0 reads done
  STAGESC(1, 0, cA);
  STAGESC(1, 1, cB);
  __syncthreads();                          // mc1 staged

  #pragma unroll
  for (int ks = 4; ks < 8; ks++) {
    if (ks < 7) LOADB(ks + 1);
    const int cc = (ks >> 1) & 1, kk = ks & 1;
    const int p = ((kk << 2) + (lane >> 4)) ^ (lane & 7);
    const char* lb = smem + cc*8192;
    #pragma unroll
    for (int mi = 0; mi < 4; mi++) {
      const int ro = (mi*16 + lrow)*128 + p*16;
      bf16x8 ac = *(const bf16x8*)(lb + ro);
      bf16x8 aq = *(const bf16x8*)(lb + 16384 + ro);
      #pragma unroll
      for (int ni = 0; ni < 2; ni++) {
        acc[mi][ni] = __builtin_amdgcn_mfma_f32_16x16x32_bf16(ac, breg[ks&1][ni*3+0], acc[mi][ni], 0, 0, 0);
        acc[mi][ni] = __builtin_amdgcn_mfma_f32_16x16x32_bf16(aq, breg[ks&1][ni*3+1], acc[mi][ni], 0, 0, 0);
      }
      if (NS == 3) {
        bf16x8 am = *(const bf16x8*)(lb + 32768 + ro);
        #pragma unroll
        for (int ni = 0; ni < 2; ni++)
          acc[mi][ni] = __builtin_amdgcn_mfma_f32_16x16x32_bf16(am, breg[ks&1][ni*3+2], acc[mi][ni], 0, 0, 0);
      }
    }
  }

  // epilogue: tanh + w2-dot, reduce over h; esc = exp(score) (masked -> 0)
  float hbv[2], w2v[2];
  #pragma unroll
  for (int ni = 0; ni < 2; ni++) {
    const int col = n0 + ni*16 + lrow;
    hbv[ni] = hb[b*H + col];
    w2v[ni] = w2[col];
  }
  #pragma unroll
  for (int mi = 0; mi < 4; mi++) {
    #pragma unroll
    for (int j = 0; j < 4; j++) {
      float ps = 0.f;
      #pragma unroll
      for (int ni = 0; ni < 2; ni++) {
        float x = acc[mi][ni][j] + hbv[ni];
        float ex = __expf(2.f * x);
        float th = 1.f - 2.f * __builtin_amdgcn_rcpf(ex + 1.f);
        ps += th * w2v[ni];
      }
      ps += __shfl_xor(ps, 1, 64);
      ps += __shfl_xor(ps, 2, 64);
      ps += __shfl_xor(ps, 4, 64);
      ps += __shfl_xor(ps, 8, 64);
      if (lrow == 0) red[wave][mi*16 + (lane >> 4)*4 + j] = ps;
    }
  }
  __syncthreads();
  const int ch = r0l >> 6;
  if (t < 64) {
    float s = red[0][t] + red[1][t] + red[2][t] + red[3][t]
            + red[4][t] + red[5][t] + red[6][t] + red[7][t] + b2[0];
    float ev = (r0l + t < len) ? __expf(s) : 0.f;
    esc[b*S + r0l + t] = ev;
    esh2[t] = ev;
    float v = waveReduceSum(ev);
    if (t == 0) ssum[ch*B + b] = v;
  }
  __syncthreads();

  // fused epart: 64x256 weighted sum of CBF rows (L2-hot) with esh2 weights.
  float* racc = (float*)smem;               // 16 x 256 floats (stage LDS dead)
  const int cg = t & 31, rg = t >> 5;       // 32 col-groups x 16 row-groups
  float a8[8];
  #pragma unroll
  for (int i = 0; i < 8; i++) a8[i] = 0.f;
  #pragma unroll
  for (int j = 0; j < 4; j++) {
    const int sr = rg + j*16;
    const bf16x8 cv = *(const bf16x8*)(CBF + (size_t)(rowg + sr)*D + cg*8);
    const float a = esh2[sr];
    #pragma unroll
    for (int i = 0; i < 8; i++) a8[i] += a * (float)cv[i];
  }
  *(float4*)(&racc[rg*256 + cg*8])     = *(float4*)(a8);
  *(float4*)(&racc[rg*256 + cg*8 + 4]) = *(float4*)(a8 + 4);
  __syncthreads();
  if (t < 256) {
    float s2 = 0.f;
    #pragma unroll
    for (int g = 0; g < 16; g++) s2 += racc[g*256 + t];
    epart[(ch*B + b)*D + t] = s2;
  }
}

// gru v3: T_b reduce + att write + normalized e + GRU gates. (NCH=64)
__global__ __launch_bounds__(256) void k_gru3(
    const float* __restrict__ wih, const float* __restrict__ whh,
    const float* __restrict__ bih, const float* __restrict__ bhh,
    const float* __restrict__ epart, const float* __restrict__ ssum,
    const float* __restrict__ esc, const int* __restrict__ len_c,
    const float* __restrict__ min_,
    float* __restrict__ att, float* __restrict__ mout,
    float* __restrict__ out, const int write_out) {
  const int blk = blockIdx.x;         // B*16
  const int b = blk >> 4;
  const int p = blk & 15;
  const int t = threadIdx.x;
  const int lane = t & 63, wave = t >> 6;
  const int len = len_c[b];
  __shared__ float es[D], ms[D];
  __shared__ float Tsh;
  if (t < 64) {
    float v = waveReduceSum(ssum[t*B + b]);
    if (t == 0) Tsh = v;
  }
  float e = 0.f;
  #pragma unroll
  for (int ch = 0; ch < NCH; ch++) e += epart[(ch*B + b)*D + t];
  ms[t] = min_[b*D + t];
  __syncthreads();
  const float Tinv = 1.f / Tsh;
  es[t] = e * Tinv;
  const int sI = p*256 + t;
  att[b*S + sI] = (sI < len) ? esc[b*S + sI] * Tinv : 0.f;
  __syncthreads();
  const int t0 = p << 4;
  const int l4 = lane * 4;
  float4 e4 = *(const float4*)(es + l4);
  float4 m4 = *(const float4*)(ms + l4);
  #pragma unroll
  for (int tl = 0; tl < 4; tl++) {
    const int tt = t0 + wave*4 + tl;
    float g[6];
    #pragma unroll
    for (int gg = 0; gg < 3; gg++) {
      const int j = gg*D + tt;
      const float4 wi4 = *(const float4*)(wih + (size_t)j*D + l4);
      const float4 wh4 = *(const float4*)(whh + (size_t)j*D + l4);
      float gi = e4.x*wi4.x + e4.y*wi4.y + e4.z*wi4.z + e4.w*wi4.w;
      float gh = m4.x*wh4.x + m4.y*wh4.y + m4.z*wh4.z + m4.w*wh4.w;
      g[gg]   = waveReduceSum(gi);
      g[3+gg] = waveReduceSum(gh);
    }
    if (lane == 0) {
      const int j0 = tt, j1 = D + tt, j2 = 2*D + tt;
      float gir = g[0] + bih[j0], giz = g[1] + bih[j1], gin = g[2] + bih[j2];
      float ghr = g[3] + bhh[j0], ghz = g[4] + bhh[j1], ghn = g[5] + bhh[j2];
      float rr = 1.f / (1.f + __expf(-(gir + ghr)));
      float zz = 1.f / (1.f + __expf(-(giz + ghz)));
      float nn = tanhf(gin + rr * ghn);
      float mn = (1.f - zz)*nn + zz*ms[tt];
      mout[b*D + tt] = mn;
      if (write_out) out[b*D + tt] = mn;
    }
  }
}

extern "C" void kernel_launch(void* const* d_in, const int* in_sizes, int n_in,
                              void* d_out, int out_size, void* d_ws, size_t ws_size,
                              hipStream_t stream) {
  const float* c   = (const float*)d_in[0];
  const float* q   = (const float*)d_in[1];
  const int*   len = (const int*)d_in[2];
  const float* A   = (const float*)d_in[3];
  const float* w1  = (const float*)d_in[4];
  const float* b1  = (const float*)d_in[5];
  const float* w2  = (const float*)d_in[6];
  const float* b2  = (const float*)d_in[7];
  const float* wih = (const float*)d_in[8];
  const float* whh = (const float*)d_in[9];
  const float* bih = (const float*)d_in[10];
  const float* bhh = (const float*)d_in[11];
  float* out = (float*)d_out;

  bf16_t* WCB  = (bf16_t*)d_ws;
  bf16_t* WAQ  = WCB + (size_t)B*DH;
  bf16_t* WAM  = WAQ + DH;
  bf16_t* WAQM = WAM + DH;
  bf16_t* CBF  = WAQM + DH;
  float* fb = (float*)(CBF + (size_t)R*D);
  float* vq    = fb;
  float* vm    = vq + B*D;
  float* hb    = vm + B*D;
  float* m0    = hb + B*H;
  float* m1    = m0 + B*D;
  float* epart = m1 + B*D;
  float* esc   = epart + (size_t)NCH*B*D;
  float* ssum  = esc + R;

  k_init<<<R*D/2048 + DH/256 + B*64 + B, 256, 0, stream>>>(
      c, q, w1, A, b1, len, CBF, WAQ, WAM, WAQM, vq, hb, m0, epart, ssum);

  for (int it = 0; it < 3; ++it) {
    float* min_ = (it & 1) ? m1 : m0;
    float* mout = (it & 1) ? m0 : m1;
    if (it == 0) {
      // hop 0: m == q -> vm = vq; hb precomputed in k_init; collapsed streams
      k_comb<<<B*DH/256, 256, 0, stream>>>(w1, q, min_, vq, vq, WCB);
      k_score8<2><<<R/64, 512, 0, stream>>>(CBF, WCB, WAQM, WAM, q, min_, len, hb, w2, b2, esc, epart, ssum);
    } else {
      k_pm2<<<B*64, 256, 0, stream>>>(A, w1, b1, q, min_, vm, hb);
      k_comb<<<B*DH/256, 256, 0, stream>>>(w1, q, min_, vq, vm, WCB);
      k_score8<3><<<R/64, 512, 0, stream>>>(CBF, WCB, WAQ, WAM, q, min_, len, hb, w2, b2, esc, epart, ssum);
    }
    float* att = out + B*D + (size_t)it*R;
    k_gru3<<<B*16, 256, 0, stream>>>(wih, whh, bih, bhh, epart, ssum, esc, len, min_, att, mout, out, it == 2 ? 1 : 0);
  }
}